// Round 4
// baseline (910.428 us; speedup 1.0000x reference)
//
#include <hip/hip_runtime.h>

#define S_LEN 4096
#define DIM 64
#define NHEAD 64        // B*H = 4*16
#define NCHUNK 8
#define PHEAD 4160      // 65*64 floats per head: rows e=0..63 are KV^T (e-major), row 64 = Ksum
#define LDR 68          // pass1 LDS row stride (floats)

__device__ __forceinline__ float elu1(float x) {
    // elu(x)+1 : x>0 -> x+1 ; x<=0 -> exp(x)
    return x > 0.0f ? x + 1.0f : __expf(x);
}

// ---------------- pass 1: partial KV (64x64, e-major) + Ksum per (head, chunk) ----------
// 512-thread blocks, 8 independent waves; each wave owns 64 rows (8 tiles of 8),
// single-buffered wave-private LDS staging with register prefetch of the next tile.
// 34.8 KB LDS/block -> 4 blocks/CU possible; VGPR-capped at ~16 waves/CU (2x round 3).
__global__ __launch_bounds__(512, 4) void pass1_kv(
    const float* __restrict__ K, const float* __restrict__ V,
    const float* __restrict__ mask, float* __restrict__ partials)
{
    const int head = blockIdx.x >> 3;
    const int blkc = blockIdx.x & 7;
    const int t    = threadIdx.x;
    const int lane = t & 63;
    const int wave = t >> 6;          // 0..7
    const int ex   = lane & 7;        // e-group: V cols e0..e0+7
    const int dy   = lane >> 3;       // d-group: K cols d0..d0+7
    const int e0   = ex * 8;
    const int d0   = dy * 8;

    const int srow0 = blkc * 512 + wave * 64;   // this wave's first row

    __shared__ float sm[8][2][8 * LDR];         // [wave][K/V][8 rows] = 34816 B

    const long hbase = (long)head * S_LEN * DIM;

    float acc[8][8];
    #pragma unroll
    for (int i = 0; i < 8; ++i)
        #pragma unroll
        for (int j = 0; j < 8; ++j) acc[i][j] = 0.f;
    float ks[8] = {0.f,0.f,0.f,0.f,0.f,0.f,0.f,0.f};

    float4 kr[2], vr[2];
    float  mr[2];
    auto load_tile = [&](int tile) {
        const int srow = srow0 + tile * 8;
        #pragma unroll
        for (int j = 0; j < 2; ++j) {
            const int v4   = j * 64 + lane;
            const int row  = v4 >> 4;           // 0..7
            const int colg = (v4 & 15) * 4;
            kr[j] = *(const float4*)(K + hbase + (long)(srow + row) * DIM + colg);
            vr[j] = *(const float4*)(V + hbase + (long)(srow + row) * DIM + colg);
            mr[j] = mask[head * S_LEN + srow + row];
        }
    };

    float* kf = sm[wave][0];
    float* vf = sm[wave][1];

    load_tile(0);
    for (int tile = 0; tile < 8; ++tile) {
        // featurize + write current tile (regs -> LDS); same-wave WAR on the slab is
        // preserved by program order
        #pragma unroll
        for (int j = 0; j < 2; ++j) {
            const int v4   = j * 64 + lane;
            const int row  = v4 >> 4;
            const int colg = (v4 & 15) * 4;
            float4 ko;
            ko.x = elu1(kr[j].x) * mr[j]; ko.y = elu1(kr[j].y) * mr[j];
            ko.z = elu1(kr[j].z) * mr[j]; ko.w = elu1(kr[j].w) * mr[j];
            *(float4*)&kf[row * LDR + colg] = ko;
            *(float4*)&vf[row * LDR + colg] = vr[j];
        }
        // issue next tile's global loads now; they complete under compute below
        if (tile + 1 < 8) load_tile(tile + 1);
        __builtin_amdgcn_wave_barrier();
        #pragma unroll 2
        for (int s = 0; s < 8; ++s) {
            float kk[8], vv[8];
            *(float4*)&kk[0] = *(const float4*)&kf[s * LDR + d0];
            *(float4*)&kk[4] = *(const float4*)&kf[s * LDR + d0 + 4];
            *(float4*)&vv[0] = *(const float4*)&vf[s * LDR + e0];
            *(float4*)&vv[4] = *(const float4*)&vf[s * LDR + e0 + 4];
            #pragma unroll
            for (int ei = 0; ei < 8; ++ei)
                #pragma unroll
                for (int di = 0; di < 8; ++di)
                    acc[ei][di] += kk[di] * vv[ei];
            #pragma unroll
            for (int di = 0; di < 8; ++di) ks[di] += kk[di];
        }
        __builtin_amdgcn_wave_barrier();
    }

    // -------- in-block serial reduce of the 8 wave-partials via LDS --------
    __syncthreads();
    float* red = (float*)sm;   // 4160 floats of the 34.8 KB pool
    for (int w = 0; w < 8; ++w) {
        if (wave == w) {
            if (w == 0) {
                #pragma unroll
                for (int ei = 0; ei < 8; ++ei) {
                    *(float4*)&red[(e0 + ei) * 64 + d0]     = make_float4(acc[ei][0], acc[ei][1], acc[ei][2], acc[ei][3]);
                    *(float4*)&red[(e0 + ei) * 64 + d0 + 4] = make_float4(acc[ei][4], acc[ei][5], acc[ei][6], acc[ei][7]);
                }
                if (ex == 0) {
                    *(float4*)&red[4096 + d0]     = make_float4(ks[0], ks[1], ks[2], ks[3]);
                    *(float4*)&red[4096 + d0 + 4] = make_float4(ks[4], ks[5], ks[6], ks[7]);
                }
            } else {
                #pragma unroll
                for (int ei = 0; ei < 8; ++ei) {
                    float4 a = *(float4*)&red[(e0 + ei) * 64 + d0];
                    a.x += acc[ei][0]; a.y += acc[ei][1]; a.z += acc[ei][2]; a.w += acc[ei][3];
                    *(float4*)&red[(e0 + ei) * 64 + d0] = a;
                    float4 b = *(float4*)&red[(e0 + ei) * 64 + d0 + 4];
                    b.x += acc[ei][4]; b.y += acc[ei][5]; b.z += acc[ei][6]; b.w += acc[ei][7];
                    *(float4*)&red[(e0 + ei) * 64 + d0 + 4] = b;
                }
                if (ex == 0) {
                    float4 a = *(float4*)&red[4096 + d0];
                    a.x += ks[0]; a.y += ks[1]; a.z += ks[2]; a.w += ks[3];
                    *(float4*)&red[4096 + d0] = a;
                    float4 b = *(float4*)&red[4096 + d0 + 4];
                    b.x += ks[4]; b.y += ks[5]; b.z += ks[6]; b.w += ks[7];
                    *(float4*)&red[4096 + d0 + 4] = b;
                }
            }
        }
        __syncthreads();
    }
    float* P = partials + (long)(head * NCHUNK + blkc) * PHEAD;
    for (int i = t; i < PHEAD / 4; i += 512)
        *(float4*)(P + i * 4) = *(const float4*)&red[i * 4];
}

// ---------------- reduce: sum NCHUNK partials -> final KV^T (+Ksum) per head ----------------
__global__ __launch_bounds__(256) void reduce_kv(
    const float* __restrict__ partials, float* __restrict__ kvf)
{
    const int head  = blockIdx.x >> 3;
    const int slice = blockIdx.x & 7;
    const int lo = slice * (PHEAD / 8);
    const int hi = lo + (PHEAD / 8);
    for (int idx = lo + threadIdx.x; idx < hi; idx += 256) {
        float s = 0.f;
        #pragma unroll
        for (int c = 0; c < NCHUNK; ++c)
            s += partials[((long)head * NCHUNK + c) * PHEAD + idx];
        kvf[(long)head * PHEAD + idx] = s;
    }
}

// ---------------- pass 2: out = (Qf @ KV) / (Qf . Ksum) ----------------
// Block = 64 rows (grid 4096). Lane = row, full Qf row in 64 VGPRs; the 4 waves split
// the 16 column-groups (4 each), so per-wave s_load streams stay block-uniform.
// Q staged once in a shared swizzled 16 KB slab with FULL 256 B row loads; per-eg
// results land in a second 16 KB slab; final store phase writes FULL 256 B rows
// (round-3 counters showed 128 B half-row phases double HBM traffic: 256 B sectors).
__global__ __launch_bounds__(256, 4) void pass2_out(
    const float* __restrict__ Q, const float* __restrict__ kvf,
    float* __restrict__ out)
{
    const int head = blockIdx.x >> 6;     // 64 tiles of 64 rows per head
    const int tile = blockIdx.x & 63;
    const int t    = threadIdx.x;
    const int lane = t & 63;
    const int wave = t >> 6;

    __shared__ float q_sl[64 * 64];       // swizzled Qf tile, 16 KB
    __shared__ float o_sl[64 * 64];       // swizzled output tile, 16 KB

    const long hbase = (long)head * S_LEN * DIM;
    const int  rbase = tile * 64;

    // (a) stage Q tile: full 256 B rows, coalesced; XOR-swizzle (proven 0-conflict family)
    #pragma unroll
    for (int i = 0; i < 4; ++i) {
        const int v4  = i * 256 + t;
        const int row = v4 >> 4;
        const int g   = v4 & 15;
        const float4 qv = *(const float4*)(Q + hbase + (long)(rbase + row) * DIM + g * 4);
        float4 qo;
        qo.x = elu1(qv.x); qo.y = elu1(qv.y); qo.z = elu1(qv.z); qo.w = elu1(qv.w);
        *(float4*)&q_sl[row * 64 + ((g ^ (row & 15)) * 4)] = qo;
    }
    __syncthreads();

    // (b) each lane pulls its entire row into registers
    float q[64];
    #pragma unroll
    for (int g = 0; g < 16; ++g) {
        const float4 v = *(const float4*)&q_sl[lane * 64 + ((g ^ (lane & 15)) * 4)];
        q[g * 4 + 0] = v.x; q[g * 4 + 1] = v.y; q[g * 4 + 2] = v.z; q[g * 4 + 3] = v.w;
    }

    const float* __restrict__ kvt = kvf + (long)head * PHEAD;

    // denominator: Qf . Ksum — uniform address -> scalar loads
    float denom = 0.f;
    #pragma unroll
    for (int d = 0; d < 64; ++d) denom += q[d] * kvt[64 * 64 + d];
    const float rz = 1.0f / denom;

    // (c) this wave's 4 column-groups (16 cols); kvt rows block-uniform -> s_load bursts
    #pragma unroll 1
    for (int j = 0; j < 4; ++j) {
        const int cg = wave * 4 + j;                    // 0..15
        const float* __restrict__ r = kvt + cg * 256;   // rows e = 4*cg .. 4*cg+3
        float a[4];
        #pragma unroll
        for (int er = 0; er < 4; ++er) {
            float s = 0.f;
            #pragma unroll
            for (int d = 0; d < 64; ++d) s += q[d] * r[er * 64 + d];
            a[er] = s;
        }
        *(float4*)&o_sl[lane * 64 + ((cg ^ (lane & 15)) * 4)] =
            make_float4(a[0] * rz, a[1] * rz, a[2] * rz, a[3] * rz);
    }
    __syncthreads();

    // (d) readback (unswizzle) + full 256 B row coalesced stores
    #pragma unroll
    for (int i = 0; i < 4; ++i) {
        const int v4  = i * 256 + t;
        const int row = v4 >> 4;
        const int g   = v4 & 15;
        const float4 o = *(const float4*)&o_sl[row * 64 + ((g ^ (row & 15)) * 4)];
        *(float4*)(out + hbase + (long)(rbase + row) * DIM + g * 4) = o;
    }
}

extern "C" void kernel_launch(void* const* d_in, const int* in_sizes, int n_in,
                              void* d_out, int out_size, void* d_ws, size_t ws_size,
                              hipStream_t stream) {
    const float* Q    = (const float*)d_in[0];
    const float* K    = (const float*)d_in[1];
    const float* V    = (const float*)d_in[2];
    const float* mask = (const float*)d_in[3];
    float* out = (float*)d_out;

    float* partials = (float*)d_ws;                            // 64*8*4160 floats ≈ 8.5 MB
    float* kvf = partials + (size_t)NHEAD * NCHUNK * PHEAD;    // + ≈1.1 MB (proven fit)

    pass1_kv<<<NHEAD * NCHUNK, 512, 0, stream>>>(K, V, mask, partials);
    reduce_kv<<<NHEAD * 8, 256, 0, stream>>>(partials, kvf);
    pass2_out<<<NHEAD * 64, 256, 0, stream>>>(Q, kvf, out);
}

// Round 5
// 322.577 us; speedup vs baseline: 2.8224x; 2.8224x over previous
//
#include <hip/hip_runtime.h>

#define S_LEN 4096
#define DIM 64
#define NHEAD 64        // B*H = 4*16
#define NCHUNK 8
#define PHEAD 4160      // 65*64 floats per head: rows e=0..63 are KV^T (e-major), row 64 = Ksum
#define LDR 68          // pass1 LDS row stride (floats)

__device__ __forceinline__ float elu1(float x) {
    // elu(x)+1 : x>0 -> x+1 ; x<=0 -> exp(x)
    return x > 0.0f ? x + 1.0f : __expf(x);
}

// ---------------- pass 1: partial KV (64x64, e-major) + Ksum per (head, chunk) ----------
// 512-thread blocks, 8 independent waves; each wave owns 64 rows (8 tiles of 8),
// single-buffered wave-private LDS staging with register prefetch of the next tile.
// NO min-occupancy clamp: q/acc arrays must stay in VGPRs (round-4 lesson: a clamp
// that forces spill turns this kernel scratch-bound).
__global__ __launch_bounds__(512) void pass1_kv(
    const float* __restrict__ K, const float* __restrict__ V,
    const float* __restrict__ mask, float* __restrict__ partials)
{
    const int head = blockIdx.x >> 3;
    const int blkc = blockIdx.x & 7;
    const int t    = threadIdx.x;
    const int lane = t & 63;
    const int wave = t >> 6;          // 0..7
    const int ex   = lane & 7;        // e-group: V cols e0..e0+7
    const int dy   = lane >> 3;       // d-group: K cols d0..d0+7
    const int e0   = ex * 8;
    const int d0   = dy * 8;

    const int srow0 = blkc * 512 + wave * 64;   // this wave's first row

    __shared__ float sm[8][2][8 * LDR];         // [wave][K/V][8 rows] = 34816 B

    const long hbase = (long)head * S_LEN * DIM;

    float acc[8][8];
    #pragma unroll
    for (int i = 0; i < 8; ++i)
        #pragma unroll
        for (int j = 0; j < 8; ++j) acc[i][j] = 0.f;
    float ks[8] = {0.f,0.f,0.f,0.f,0.f,0.f,0.f,0.f};

    float4 kr[2], vr[2];
    float  mr[2];
    auto load_tile = [&](int tile) {
        const int srow = srow0 + tile * 8;
        #pragma unroll
        for (int j = 0; j < 2; ++j) {
            const int v4   = j * 64 + lane;
            const int row  = v4 >> 4;           // 0..7
            const int colg = (v4 & 15) * 4;
            kr[j] = *(const float4*)(K + hbase + (long)(srow + row) * DIM + colg);
            vr[j] = *(const float4*)(V + hbase + (long)(srow + row) * DIM + colg);
            mr[j] = mask[head * S_LEN + srow + row];
        }
    };

    float* kf = sm[wave][0];
    float* vf = sm[wave][1];

    load_tile(0);
    for (int tile = 0; tile < 8; ++tile) {
        // featurize + write current tile (regs -> LDS); same-wave ordering is program order
        #pragma unroll
        for (int j = 0; j < 2; ++j) {
            const int v4   = j * 64 + lane;
            const int row  = v4 >> 4;
            const int colg = (v4 & 15) * 4;
            float4 ko;
            ko.x = elu1(kr[j].x) * mr[j]; ko.y = elu1(kr[j].y) * mr[j];
            ko.z = elu1(kr[j].z) * mr[j]; ko.w = elu1(kr[j].w) * mr[j];
            *(float4*)&kf[row * LDR + colg] = ko;
            *(float4*)&vf[row * LDR + colg] = vr[j];
        }
        // issue next tile's global loads now; they complete under compute below
        if (tile + 1 < 8) load_tile(tile + 1);
        __builtin_amdgcn_wave_barrier();
        #pragma unroll 2
        for (int s = 0; s < 8; ++s) {
            float kk[8], vv[8];
            *(float4*)&kk[0] = *(const float4*)&kf[s * LDR + d0];
            *(float4*)&kk[4] = *(const float4*)&kf[s * LDR + d0 + 4];
            *(float4*)&vv[0] = *(const float4*)&vf[s * LDR + e0];
            *(float4*)&vv[4] = *(const float4*)&vf[s * LDR + e0 + 4];
            #pragma unroll
            for (int ei = 0; ei < 8; ++ei)
                #pragma unroll
                for (int di = 0; di < 8; ++di)
                    acc[ei][di] += kk[di] * vv[ei];
            #pragma unroll
            for (int di = 0; di < 8; ++di) ks[di] += kk[di];
        }
        __builtin_amdgcn_wave_barrier();
    }

    // -------- in-block serial reduce of the 8 wave-partials via LDS --------
    __syncthreads();
    float* red = (float*)sm;   // 4160 floats of the 34.8 KB pool
    for (int w = 0; w < 8; ++w) {
        if (wave == w) {
            if (w == 0) {
                #pragma unroll
                for (int ei = 0; ei < 8; ++ei) {
                    *(float4*)&red[(e0 + ei) * 64 + d0]     = make_float4(acc[ei][0], acc[ei][1], acc[ei][2], acc[ei][3]);
                    *(float4*)&red[(e0 + ei) * 64 + d0 + 4] = make_float4(acc[ei][4], acc[ei][5], acc[ei][6], acc[ei][7]);
                }
                if (ex == 0) {
                    *(float4*)&red[4096 + d0]     = make_float4(ks[0], ks[1], ks[2], ks[3]);
                    *(float4*)&red[4096 + d0 + 4] = make_float4(ks[4], ks[5], ks[6], ks[7]);
                }
            } else {
                #pragma unroll
                for (int ei = 0; ei < 8; ++ei) {
                    float4 a = *(float4*)&red[(e0 + ei) * 64 + d0];
                    a.x += acc[ei][0]; a.y += acc[ei][1]; a.z += acc[ei][2]; a.w += acc[ei][3];
                    *(float4*)&red[(e0 + ei) * 64 + d0] = a;
                    float4 b = *(float4*)&red[(e0 + ei) * 64 + d0 + 4];
                    b.x += acc[ei][4]; b.y += acc[ei][5]; b.z += acc[ei][6]; b.w += acc[ei][7];
                    *(float4*)&red[(e0 + ei) * 64 + d0 + 4] = b;
                }
                if (ex == 0) {
                    float4 a = *(float4*)&red[4096 + d0];
                    a.x += ks[0]; a.y += ks[1]; a.z += ks[2]; a.w += ks[3];
                    *(float4*)&red[4096 + d0] = a;
                    float4 b = *(float4*)&red[4096 + d0 + 4];
                    b.x += ks[4]; b.y += ks[5]; b.z += ks[6]; b.w += ks[7];
                    *(float4*)&red[4096 + d0 + 4] = b;
                }
            }
        }
        __syncthreads();
    }
    float* P = partials + (long)(head * NCHUNK + blkc) * PHEAD;
    for (int i = t; i < PHEAD / 4; i += 512)
        *(float4*)(P + i * 4) = *(const float4*)&red[i * 4];
}

// ---------------- reduce: sum NCHUNK partials -> final KV^T (+Ksum) per head ----------------
__global__ __launch_bounds__(256) void reduce_kv(
    const float* __restrict__ partials, float* __restrict__ kvf)
{
    const int head  = blockIdx.x >> 3;
    const int slice = blockIdx.x & 7;
    const int lo = slice * (PHEAD / 8);
    const int hi = lo + (PHEAD / 8);
    for (int idx = lo + threadIdx.x; idx < hi; idx += 256) {
        float s = 0.f;
        #pragma unroll
        for (int c = 0; c < NCHUNK; ++c)
            s += partials[((long)head * NCHUNK + c) * PHEAD + idx];
        kvf[(long)head * PHEAD + idx] = s;
    }
}

// ---------------- pass 2: out = (Qf @ KV) / (Qf . Ksum) ----------------
// Lane = row, full Qf row in 64 VGPRs; cg loop is block-uniform (round-2-proven
// codegen: KV goes through the scalar s_load pipe, inner loop is v_fmac w/ SGPR src).
// ZERO LDS, zero barriers: Q rows loaded per-lane directly (16 B/lane @ 256 B stride;
// each 64 B sector reused by 4 consecutive iterations via L1 -> exact HBM traffic),
// outputs stored per-lane directly (sector completed by 4 adjacent cg iters -> L2
// merge -> exact traffic). NO launch_bounds min-occupancy clamp: q[64] MUST stay in
// VGPRs (round-4 lesson: VGPR=64 clamp spilled q -> 2.9 GB scratch traffic, 6.7x).
__global__ __launch_bounds__(256) void pass2_out(
    const float* __restrict__ Q, const float* __restrict__ kvf,
    float* __restrict__ out)
{
    const int head = blockIdx.x >> 4;     // 16 tiles of 256 rows per head
    const int tile = blockIdx.x & 15;
    const int lane = threadIdx.x & 63;
    const int wave = threadIdx.x >> 6;

    const long hbase = (long)head * S_LEN * DIM;
    const int  row   = tile * 256 + wave * 64 + lane;   // this lane's row

    // (a) pull own Qf row into registers, elu+1 applied on the fly
    const float* __restrict__ qrow = Q + hbase + (long)row * DIM;
    float q[64];
    #pragma unroll
    for (int i = 0; i < 16; ++i) {
        const float4 v = *(const float4*)(qrow + i * 4);
        q[i * 4 + 0] = elu1(v.x); q[i * 4 + 1] = elu1(v.y);
        q[i * 4 + 2] = elu1(v.z); q[i * 4 + 3] = elu1(v.w);
    }

    const float* __restrict__ kvt = kvf + (long)head * PHEAD;

    // (b) denominator: Qf . Ksum — uniform address -> scalar loads
    float denom = 0.f;
    #pragma unroll
    for (int d = 0; d < 64; ++d) denom += q[d] * kvt[64 * 64 + d];
    const float rz = 1.0f / denom;

    // (c) 16 column-groups, block-uniform loop; kvt rows -> s_load bursts;
    //     direct float4 store of cols [4cg, 4cg+4) of own row
    float* __restrict__ orow = out + hbase + (long)row * DIM;
    #pragma unroll 1
    for (int cg = 0; cg < 16; ++cg) {
        const float* __restrict__ r = kvt + cg * 256;   // rows e = 4*cg .. 4*cg+3
        float a[4];
        #pragma unroll
        for (int er = 0; er < 4; ++er) {
            float s = 0.f;
            #pragma unroll
            for (int d = 0; d < 64; ++d) s += q[d] * r[er * 64 + d];
            a[er] = s;
        }
        *(float4*)(orow + cg * 4) = make_float4(a[0] * rz, a[1] * rz, a[2] * rz, a[3] * rz);
    }
}

extern "C" void kernel_launch(void* const* d_in, const int* in_sizes, int n_in,
                              void* d_out, int out_size, void* d_ws, size_t ws_size,
                              hipStream_t stream) {
    const float* Q    = (const float*)d_in[0];
    const float* K    = (const float*)d_in[1];
    const float* V    = (const float*)d_in[2];
    const float* mask = (const float*)d_in[3];
    float* out = (float*)d_out;

    float* partials = (float*)d_ws;                            // 64*8*4160 floats ≈ 8.5 MB
    float* kvf = partials + (size_t)NHEAD * NCHUNK * PHEAD;    // + ≈1.1 MB (proven fit)

    pass1_kv<<<NHEAD * NCHUNK, 512, 0, stream>>>(K, V, mask, partials);
    reduce_kv<<<NHEAD * 8, 256, 0, stream>>>(partials, kvf);
    pass2_out<<<NHEAD * 16, 256, 0, stream>>>(Q, kvf, out);
}

// Round 6
// 305.856 us; speedup vs baseline: 2.9767x; 1.0547x over previous
//
#include <hip/hip_runtime.h>

#define S_LEN 4096
#define DIM 64
#define NHEAD 64        // B*H = 4*16
#define NCHUNK 8
#define PHEAD 4160      // 65*64 floats per head: rows e=0..63 are KV^T (e-major), row 64 = Ksum
#define LDR 68          // pass1 LDS row stride (floats)

__device__ __forceinline__ float elu1(float x) {
    // elu(x)+1 : x>0 -> x+1 ; x<=0 -> exp(x)
    return x > 0.0f ? x + 1.0f : __expf(x);
}

// ---------------- pass 1: partial KV (64x64, e-major) + Ksum per (head, chunk) ----------
// (unchanged from round 5 — next optimization target, kept identical for attribution)
__global__ __launch_bounds__(512) void pass1_kv(
    const float* __restrict__ K, const float* __restrict__ V,
    const float* __restrict__ mask, float* __restrict__ partials)
{
    const int head = blockIdx.x >> 3;
    const int blkc = blockIdx.x & 7;
    const int t    = threadIdx.x;
    const int lane = t & 63;
    const int wave = t >> 6;          // 0..7
    const int ex   = lane & 7;        // e-group: V cols e0..e0+7
    const int dy   = lane >> 3;       // d-group: K cols d0..d0+7
    const int e0   = ex * 8;
    const int d0   = dy * 8;

    const int srow0 = blkc * 512 + wave * 64;   // this wave's first row

    __shared__ float sm[8][2][8 * LDR];         // [wave][K/V][8 rows] = 34816 B

    const long hbase = (long)head * S_LEN * DIM;

    float acc[8][8];
    #pragma unroll
    for (int i = 0; i < 8; ++i)
        #pragma unroll
        for (int j = 0; j < 8; ++j) acc[i][j] = 0.f;
    float ks[8] = {0.f,0.f,0.f,0.f,0.f,0.f,0.f,0.f};

    float4 kr[2], vr[2];
    float  mr[2];
    auto load_tile = [&](int tile) {
        const int srow = srow0 + tile * 8;
        #pragma unroll
        for (int j = 0; j < 2; ++j) {
            const int v4   = j * 64 + lane;
            const int row  = v4 >> 4;           // 0..7
            const int colg = (v4 & 15) * 4;
            kr[j] = *(const float4*)(K + hbase + (long)(srow + row) * DIM + colg);
            vr[j] = *(const float4*)(V + hbase + (long)(srow + row) * DIM + colg);
            mr[j] = mask[head * S_LEN + srow + row];
        }
    };

    float* kf = sm[wave][0];
    float* vf = sm[wave][1];

    load_tile(0);
    for (int tile = 0; tile < 8; ++tile) {
        // featurize + write current tile (regs -> LDS); same-wave ordering is program order
        #pragma unroll
        for (int j = 0; j < 2; ++j) {
            const int v4   = j * 64 + lane;
            const int row  = v4 >> 4;
            const int colg = (v4 & 15) * 4;
            float4 ko;
            ko.x = elu1(kr[j].x) * mr[j]; ko.y = elu1(kr[j].y) * mr[j];
            ko.z = elu1(kr[j].z) * mr[j]; ko.w = elu1(kr[j].w) * mr[j];
            *(float4*)&kf[row * LDR + colg] = ko;
            *(float4*)&vf[row * LDR + colg] = vr[j];
        }
        // issue next tile's global loads now; they complete under compute below
        if (tile + 1 < 8) load_tile(tile + 1);
        __builtin_amdgcn_wave_barrier();
        #pragma unroll 2
        for (int s = 0; s < 8; ++s) {
            float kk[8], vv[8];
            *(float4*)&kk[0] = *(const float4*)&kf[s * LDR + d0];
            *(float4*)&kk[4] = *(const float4*)&kf[s * LDR + d0 + 4];
            *(float4*)&vv[0] = *(const float4*)&vf[s * LDR + e0];
            *(float4*)&vv[4] = *(const float4*)&vf[s * LDR + e0 + 4];
            #pragma unroll
            for (int ei = 0; ei < 8; ++ei)
                #pragma unroll
                for (int di = 0; di < 8; ++di)
                    acc[ei][di] += kk[di] * vv[ei];
            #pragma unroll
            for (int di = 0; di < 8; ++di) ks[di] += kk[di];
        }
        __builtin_amdgcn_wave_barrier();
    }

    // -------- in-block serial reduce of the 8 wave-partials via LDS --------
    __syncthreads();
    float* red = (float*)sm;   // 4160 floats of the 34.8 KB pool
    for (int w = 0; w < 8; ++w) {
        if (wave == w) {
            if (w == 0) {
                #pragma unroll
                for (int ei = 0; ei < 8; ++ei) {
                    *(float4*)&red[(e0 + ei) * 64 + d0]     = make_float4(acc[ei][0], acc[ei][1], acc[ei][2], acc[ei][3]);
                    *(float4*)&red[(e0 + ei) * 64 + d0 + 4] = make_float4(acc[ei][4], acc[ei][5], acc[ei][6], acc[ei][7]);
                }
                if (ex == 0) {
                    *(float4*)&red[4096 + d0]     = make_float4(ks[0], ks[1], ks[2], ks[3]);
                    *(float4*)&red[4096 + d0 + 4] = make_float4(ks[4], ks[5], ks[6], ks[7]);
                }
            } else {
                #pragma unroll
                for (int ei = 0; ei < 8; ++ei) {
                    float4 a = *(float4*)&red[(e0 + ei) * 64 + d0];
                    a.x += acc[ei][0]; a.y += acc[ei][1]; a.z += acc[ei][2]; a.w += acc[ei][3];
                    *(float4*)&red[(e0 + ei) * 64 + d0] = a;
                    float4 b = *(float4*)&red[(e0 + ei) * 64 + d0 + 4];
                    b.x += acc[ei][4]; b.y += acc[ei][5]; b.z += acc[ei][6]; b.w += acc[ei][7];
                    *(float4*)&red[(e0 + ei) * 64 + d0 + 4] = b;
                }
                if (ex == 0) {
                    float4 a = *(float4*)&red[4096 + d0];
                    a.x += ks[0]; a.y += ks[1]; a.z += ks[2]; a.w += ks[3];
                    *(float4*)&red[4096 + d0] = a;
                    float4 b = *(float4*)&red[4096 + d0 + 4];
                    b.x += ks[4]; b.y += ks[5]; b.z += ks[6]; b.w += ks[7];
                    *(float4*)&red[4096 + d0 + 4] = b;
                }
            }
        }
        __syncthreads();
    }
    float* P = partials + (long)(head * NCHUNK + blkc) * PHEAD;
    for (int i = t; i < PHEAD / 4; i += 512)
        *(float4*)(P + i * 4) = *(const float4*)&red[i * 4];
}

// ---------------- reduce: sum NCHUNK partials -> final KV^T (+Ksum) per head ----------------
__global__ __launch_bounds__(256) void reduce_kv(
    const float* __restrict__ partials, float* __restrict__ kvf)
{
    const int head  = blockIdx.x >> 3;
    const int slice = blockIdx.x & 7;
    const int lo = slice * (PHEAD / 8);
    const int hi = lo + (PHEAD / 8);
    for (int idx = lo + threadIdx.x; idx < hi; idx += 256) {
        float s = 0.f;
        #pragma unroll
        for (int c = 0; c < NCHUNK; ++c)
            s += partials[((long)head * NCHUNK + c) * PHEAD + idx];
        kvf[(long)head * PHEAD + idx] = s;
    }
}

// ---------------- pass 2: out = (Qf @ KV) / (Qf . Ksum) ----------------
// 64-row blocks (grid 4096). All 4 waves cover the SAME 64 rows (lane = row, own Qf
// row in 64 VGPRs, direct per-lane loads — L1 absorbs the stride-256 sector reuse,
// proven round 5: FETCH 48 MB). Waves split the 16 column-groups 4-each; cg is pinned
// into an SGPR via readfirstlane so KV loads keep the proven s_load codegen (round-4
// lesson: threadIdx-derived cg -> divergent vector loads). Results transposed through
// one 16 KB XOR-swizzled LDS slab; store phase writes FULL 256 B rows (round-5 lesson:
// 16 B/lane direct stores -> partial-sector eviction -> 4.2x write amplification).
// NO min-occupancy clamp (round-4 lesson: forced spill of q[64]).
__global__ __launch_bounds__(256) void pass2_out(
    const float* __restrict__ Q, const float* __restrict__ kvf,
    float* __restrict__ out)
{
    const int head = blockIdx.x >> 6;     // 64 tiles of 64 rows per head
    const int tile = blockIdx.x & 63;
    const int t    = threadIdx.x;
    const int lane = t & 63;
    const int wave = t >> 6;

    __shared__ float o_sl[64 * 64];       // swizzled output tile, 16 KB

    const long hbase = (long)head * S_LEN * DIM;
    const int  rbase = tile * 64;
    const int  row   = rbase + lane;      // this lane's row (same set for all 4 waves)

    // (a) pull own Qf row into registers, elu+1 on the fly
    const float* __restrict__ qrow = Q + hbase + (long)row * DIM;
    float q[64];
    #pragma unroll
    for (int i = 0; i < 16; ++i) {
        const float4 v = *(const float4*)(qrow + i * 4);
        q[i * 4 + 0] = elu1(v.x); q[i * 4 + 1] = elu1(v.y);
        q[i * 4 + 2] = elu1(v.z); q[i * 4 + 3] = elu1(v.w);
    }

    const float* __restrict__ kvt = kvf + (long)head * PHEAD;

    // (b) denominator: Qf . Ksum — uniform address -> scalar loads
    float denom = 0.f;
    #pragma unroll
    for (int d = 0; d < 64; ++d) denom += q[d] * kvt[64 * 64 + d];
    const float rz = 1.0f / denom;

    // (c) this wave's 4 column-groups; cg0 pinned to SGPR -> kvt rows stay s_load
    const int cg0 = __builtin_amdgcn_readfirstlane(wave) * 4;
    #pragma unroll 1
    for (int j = 0; j < 4; ++j) {
        const int cg = cg0 + j;                         // block-uniform per wave
        const float* __restrict__ r = kvt + cg * 256;   // rows e = 4*cg .. 4*cg+3
        float a[4];
        #pragma unroll
        for (int er = 0; er < 4; ++er) {
            float s = 0.f;
            #pragma unroll
            for (int d = 0; d < 64; ++d) s += q[d] * r[er * 64 + d];
            a[er] = s;
        }
        *(float4*)&o_sl[lane * 64 + ((cg ^ (lane & 15)) * 4)] =
            make_float4(a[0] * rz, a[1] * rz, a[2] * rz, a[3] * rz);
    }
    __syncthreads();

    // (d) readback (unswizzle) + full 256 B row coalesced stores (exact HBM traffic)
    #pragma unroll
    for (int i = 0; i < 4; ++i) {
        const int v4  = i * 256 + t;
        const int orow = v4 >> 4;
        const int g    = v4 & 15;
        const float4 o = *(const float4*)&o_sl[orow * 64 + ((g ^ (orow & 15)) * 4)];
        *(float4*)(out + hbase + (long)(rbase + orow) * DIM + g * 4) = o;
    }
}

extern "C" void kernel_launch(void* const* d_in, const int* in_sizes, int n_in,
                              void* d_out, int out_size, void* d_ws, size_t ws_size,
                              hipStream_t stream) {
    const float* Q    = (const float*)d_in[0];
    const float* K    = (const float*)d_in[1];
    const float* V    = (const float*)d_in[2];
    const float* mask = (const float*)d_in[3];
    float* out = (float*)d_out;

    float* partials = (float*)d_ws;                            // 64*8*4160 floats ≈ 8.5 MB
    float* kvf = partials + (size_t)NHEAD * NCHUNK * PHEAD;    // + ≈1.1 MB (proven fit)

    pass1_kv<<<NHEAD * NCHUNK, 512, 0, stream>>>(K, V, mask, partials);
    reduce_kv<<<NHEAD * 8, 256, 0, stream>>>(partials, kvf);
    pass2_out<<<NHEAD * 64, 256, 0, stream>>>(Q, kvf, out);
}